// Round 14
// baseline (549.562 us; speedup 1.0000x reference)
//
#include <hip/hip_runtime.h>
#include <math.h>

#define NN 50000
#define NE 800000
#define FD 128
#define SCAN_B 196   // ceil(50176/256)
#define NTR 100000
#define NTE 20000

// ---------------- degree ----------------

__global__ __launch_bounds__(256) void k_count(const int* __restrict__ dst, int* __restrict__ deg) {
    int e = blockIdx.x * 256 + threadIdx.x;
    if (e < NE) atomicAdd(&deg[dst[e]], 1);
}

// ---------------- parallel exclusive scan of deg ----------------

__global__ __launch_bounds__(256) void k_scan1(const int* __restrict__ deg,
                                               int* __restrict__ partial,
                                               int* __restrict__ bsum,
                                               float* __restrict__ dis) {
    __shared__ int wsum[4];
    const int t = threadIdx.x, lane = t & 63, wid = t >> 6;
    const int i = blockIdx.x * 256 + t;
    int v = (i < NN) ? deg[i] : 0;
    int sc = v;
#pragma unroll
    for (int d = 1; d < 64; d <<= 1) {
        int o = __shfl_up(sc, d, 64);
        if (lane >= d) sc += o;
    }
    if (lane == 63) wsum[wid] = sc;
    __syncthreads();
    int pre = 0;
    for (int w = 0; w < wid; ++w) pre += wsum[w];
    if (i < NN) {
        partial[i] = pre + sc - v;
        dis[i] = (float)(1.0 / sqrt((double)(v + 1)));
    }
    if (t == 255) bsum[blockIdx.x] = pre + sc;
}

// scan3 (scan2 folded in): each block reduces bsum[0..bid) itself, then adds.

__global__ __launch_bounds__(256) void k_scan3(const int* __restrict__ partial,
                                               const int* __restrict__ bsum,
                                               int* __restrict__ offs,
                                               int* __restrict__ cursor) {
    __shared__ int wsum[4];
    const int t = threadIdx.x, lane = t & 63, wid = t >> 6;
    int v = (t < blockIdx.x && t < SCAN_B) ? bsum[t] : 0;
#pragma unroll
    for (int m = 32; m >= 1; m >>= 1) v += __shfl_xor(v, m, 64);
    if (lane == 0) wsum[wid] = v;
    __syncthreads();
    int pre = wsum[0] + wsum[1] + wsum[2] + wsum[3];
    const int i = blockIdx.x * 256 + t;
    if (i < NN) {
        int o = partial[i] + pre;
        offs[i] = o;
        cursor[i] = o;
    }
    if (blockIdx.x == 0 && t == 0) offs[NN] = NE;
}

// ---------------- counting-sort fill ----------------

__global__ __launch_bounds__(256) void k_fill(const int* __restrict__ src, const int* __restrict__ dst,
                                              int* __restrict__ cursor, int* __restrict__ srcs_sorted) {
    int e = blockIdx.x * 256 + threadIdx.x;
    if (e < NE) {
        int d = dst[e];
        int p = atomicAdd(&cursor[d], 1);
        srcs_sorted[p] = src[e];
    }
}

// ---------------- node GEMM (layer 0): C[r] = (A[r] @ W) * dis[r] ----------------

__global__ __launch_bounds__(256) void k_gemm(const float* __restrict__ A,
                                              const float* __restrict__ W,
                                              const float* __restrict__ dis,
                                              float* __restrict__ C, int nrows) {
    __shared__ float As[32][128];
    const int t = threadIdx.x;
    const int row0 = blockIdx.x * 32;

    for (int idx = t; idx < 32 * 32; idx += 256) {
        int r = idx >> 5, c = idx & 31;
        float4 v = make_float4(0.f, 0.f, 0.f, 0.f);
        if (row0 + r < nrows)
            v = reinterpret_cast<const float4*>(A)[(size_t)(row0 + r) * 32 + c];
        reinterpret_cast<float4*>(&As[r][0])[c] = v;
    }
    __syncthreads();

    const int cg = t & 31;
    const int eg = t >> 5;
    float acc[4][4] = {{0.f}};

    const float4* W4 = reinterpret_cast<const float4*>(W);
    const float4* As4 = reinterpret_cast<const float4*>(As);

    float4 w0 = W4[0 * 32 + cg];
    float4 w1 = W4[1 * 32 + cg];
    float4 w2 = W4[2 * 32 + cg];
    float4 w3 = W4[3 * 32 + cg];

    for (int k4 = 0; k4 < 32; ++k4) {
        int kn = (k4 < 31) ? (k4 + 1) : 31;
        float4 n0 = W4[(kn * 4 + 0) * 32 + cg];
        float4 n1 = W4[(kn * 4 + 1) * 32 + cg];
        float4 n2 = W4[(kn * 4 + 2) * 32 + cg];
        float4 n3 = W4[(kn * 4 + 3) * 32 + cg];
#pragma unroll
        for (int i = 0; i < 4; ++i) {
            float4 a = As4[(eg * 4 + i) * 32 + k4];
            acc[i][0] += a.x * w0.x + a.y * w1.x + a.z * w2.x + a.w * w3.x;
            acc[i][1] += a.x * w0.y + a.y * w1.y + a.z * w2.y + a.w * w3.y;
            acc[i][2] += a.x * w0.z + a.y * w1.z + a.z * w2.z + a.w * w3.z;
            acc[i][3] += a.x * w0.w + a.y * w1.w + a.z * w2.w + a.w * w3.w;
        }
        w0 = n0; w1 = n1; w2 = n2; w3 = n3;
    }

#pragma unroll
    for (int i = 0; i < 4; ++i) {
        int r = row0 + eg * 4 + i;
        if (r < nrows) {
            float d = dis[r];
            float4 o = make_float4(acc[i][0] * d, acc[i][1] * d, acc[i][2] * d, acc[i][3] * d);
            reinterpret_cast<float4*>(C)[(size_t)r * 32 + cg] = o;
        }
    }
}

// ---------------- fused gather+GEMM, 32-row tile, barrier-free (R12 config + setprio) ----

__global__ __launch_bounds__(256) void k_fused_gg(const float* __restrict__ hws_in,
                                                  const float* __restrict__ dis,
                                                  const float* __restrict__ bprev,
                                                  const float* __restrict__ W,
                                                  const int* __restrict__ offs,
                                                  const int* __restrict__ srcs,
                                                  float* __restrict__ hws_out, int nrows) {
    __shared__ float As[32][128];
    const int t = threadIdx.x;
    const int f4 = t & 31;
    const int ng = t >> 5;
    const int row0 = blockIdx.x * 32;

    const float4* H4 = reinterpret_cast<const float4*>(hws_in);
    float4 bb = reinterpret_cast<const float4*>(bprev)[f4];

#pragma unroll
    for (int j = 0; j < 4; ++j) {
        int nl = ng * 4 + j;
        int node = row0 + nl;
        float4 o = make_float4(0.f, 0.f, 0.f, 0.f);
        if (node < nrows) {
            float4 acc = H4[(size_t)node * 32 + f4];
            const int e0 = offs[node], e1 = offs[node + 1];
            int e = e0;
            for (; e + 8 <= e1; e += 8) {
                int s0 = srcs[e + 0], s1 = srcs[e + 1], s2 = srcs[e + 2], s3 = srcs[e + 3];
                int s4 = srcs[e + 4], s5 = srcs[e + 5], s6 = srcs[e + 6], s7 = srcs[e + 7];
                float4 v0 = H4[(size_t)s0 * 32 + f4];
                float4 v1 = H4[(size_t)s1 * 32 + f4];
                float4 v2 = H4[(size_t)s2 * 32 + f4];
                float4 v3 = H4[(size_t)s3 * 32 + f4];
                float4 v4 = H4[(size_t)s4 * 32 + f4];
                float4 v5 = H4[(size_t)s5 * 32 + f4];
                float4 v6 = H4[(size_t)s6 * 32 + f4];
                float4 v7 = H4[(size_t)s7 * 32 + f4];
                acc.x += ((v0.x + v1.x) + (v2.x + v3.x)) + ((v4.x + v5.x) + (v6.x + v7.x));
                acc.y += ((v0.y + v1.y) + (v2.y + v3.y)) + ((v4.y + v5.y) + (v6.y + v7.y));
                acc.z += ((v0.z + v1.z) + (v2.z + v3.z)) + ((v4.z + v5.z) + (v6.z + v7.z));
                acc.w += ((v0.w + v1.w) + (v2.w + v3.w)) + ((v4.w + v5.w) + (v6.w + v7.w));
            }
            for (; e < e1; ++e) {
                int s = srcs[e];
                float4 v = H4[(size_t)s * 32 + f4];
                acc.x += v.x; acc.y += v.y; acc.z += v.z; acc.w += v.w;
            }
            float d = dis[node];
            o.x = fmaxf(acc.x * d + bb.x, 0.f);
            o.y = fmaxf(acc.y * d + bb.y, 0.f);
            o.z = fmaxf(acc.z * d + bb.z, 0.f);
            o.w = fmaxf(acc.w * d + bb.w, 0.f);
        }
        reinterpret_cast<float4*>(&As[nl][0])[f4] = o;
    }
    asm volatile("s_waitcnt lgkmcnt(0)" ::: "memory");

    const int cg = f4;
    const int eg = ng;
    float acc[4][4] = {{0.f}};

    const float4* W4 = reinterpret_cast<const float4*>(W);
    const float4* As4 = reinterpret_cast<const float4*>(As);

    float4 w0 = W4[0 * 32 + cg];
    float4 w1 = W4[1 * 32 + cg];
    float4 w2 = W4[2 * 32 + cg];
    float4 w3 = W4[3 * 32 + cg];

    __builtin_amdgcn_s_setprio(1);
    for (int k4 = 0; k4 < 32; ++k4) {
        int kn = (k4 < 31) ? (k4 + 1) : 31;
        float4 n0 = W4[(kn * 4 + 0) * 32 + cg];
        float4 n1 = W4[(kn * 4 + 1) * 32 + cg];
        float4 n2 = W4[(kn * 4 + 2) * 32 + cg];
        float4 n3 = W4[(kn * 4 + 3) * 32 + cg];
#pragma unroll
        for (int i = 0; i < 4; ++i) {
            float4 a = As4[(eg * 4 + i) * 32 + k4];
            acc[i][0] += a.x * w0.x + a.y * w1.x + a.z * w2.x + a.w * w3.x;
            acc[i][1] += a.x * w0.y + a.y * w1.y + a.z * w2.y + a.w * w3.y;
            acc[i][2] += a.x * w0.z + a.y * w1.z + a.z * w2.z + a.w * w3.z;
            acc[i][3] += a.x * w0.w + a.y * w1.w + a.z * w2.w + a.w * w3.w;
        }
        w0 = n0; w1 = n1; w2 = n2; w3 = n3;
    }
    __builtin_amdgcn_s_setprio(0);

#pragma unroll
    for (int i = 0; i < 4; ++i) {
        int r = row0 + eg * 4 + i;
        if (r < nrows) {
            float d = dis[r];
            float4 o = make_float4(acc[i][0] * d, acc[i][1] * d, acc[i][2] * d, acc[i][3] * d);
            reinterpret_cast<float4*>(hws_out)[(size_t)r * 32 + cg] = o;
        }
    }
}

// ---------------- fused tail: gather h4 (LDS only) -> U,V in ONE merged k-loop ----------------
// Per k4: 8 W loads (Wa+Wb) + 4 A LDS reads : 128 FMAs (dual accumulators).

__global__ __launch_bounds__(256) void k_fused_uv(const float* __restrict__ hws_in,
                                                  const float* __restrict__ dis,
                                                  const float* __restrict__ bprev,
                                                  const float* __restrict__ Wa,
                                                  const float* __restrict__ Wb,
                                                  const int* __restrict__ offs,
                                                  const int* __restrict__ srcs,
                                                  float* __restrict__ U,
                                                  float* __restrict__ V, int nrows) {
    __shared__ float As[32][128];
    const int t = threadIdx.x;
    const int f4 = t & 31;
    const int ng = t >> 5;
    const int row0 = blockIdx.x * 32;

    const float4* H4 = reinterpret_cast<const float4*>(hws_in);
    float4 bb = reinterpret_cast<const float4*>(bprev)[f4];

#pragma unroll
    for (int j = 0; j < 4; ++j) {
        int nl = ng * 4 + j;
        int node = row0 + nl;
        float4 o = make_float4(0.f, 0.f, 0.f, 0.f);
        if (node < nrows) {
            float4 acc = H4[(size_t)node * 32 + f4];
            const int e0 = offs[node], e1 = offs[node + 1];
            int e = e0;
            for (; e + 8 <= e1; e += 8) {
                int s0 = srcs[e + 0], s1 = srcs[e + 1], s2 = srcs[e + 2], s3 = srcs[e + 3];
                int s4 = srcs[e + 4], s5 = srcs[e + 5], s6 = srcs[e + 6], s7 = srcs[e + 7];
                float4 v0 = H4[(size_t)s0 * 32 + f4];
                float4 v1 = H4[(size_t)s1 * 32 + f4];
                float4 v2 = H4[(size_t)s2 * 32 + f4];
                float4 v3 = H4[(size_t)s3 * 32 + f4];
                float4 v4 = H4[(size_t)s4 * 32 + f4];
                float4 v5 = H4[(size_t)s5 * 32 + f4];
                float4 v6 = H4[(size_t)s6 * 32 + f4];
                float4 v7 = H4[(size_t)s7 * 32 + f4];
                acc.x += ((v0.x + v1.x) + (v2.x + v3.x)) + ((v4.x + v5.x) + (v6.x + v7.x));
                acc.y += ((v0.y + v1.y) + (v2.y + v3.y)) + ((v4.y + v5.y) + (v6.y + v7.y));
                acc.z += ((v0.z + v1.z) + (v2.z + v3.z)) + ((v4.z + v5.z) + (v6.z + v7.z));
                acc.w += ((v0.w + v1.w) + (v2.w + v3.w)) + ((v4.w + v5.w) + (v6.w + v7.w));
            }
            for (; e < e1; ++e) {
                int s = srcs[e];
                float4 v = H4[(size_t)s * 32 + f4];
                acc.x += v.x; acc.y += v.y; acc.z += v.z; acc.w += v.w;
            }
            float d = dis[node];
            o.x = acc.x * d + bb.x;
            o.y = acc.y * d + bb.y;
            o.z = acc.z * d + bb.z;
            o.w = acc.w * d + bb.w;
        }
        reinterpret_cast<float4*>(&As[nl][0])[f4] = o;
    }
    asm volatile("s_waitcnt lgkmcnt(0)" ::: "memory");

    const int cg = f4;
    const int eg = ng;
    const float4* As4 = reinterpret_cast<const float4*>(As);
    const float4* Wa4 = reinterpret_cast<const float4*>(Wa);
    const float4* Wb4 = reinterpret_cast<const float4*>(Wb);

    float accU[4][4] = {{0.f}};
    float accV[4][4] = {{0.f}};

    __builtin_amdgcn_s_setprio(1);
    for (int k4 = 0; k4 < 32; ++k4) {
        float4 wa0 = Wa4[(k4 * 4 + 0) * 32 + cg];
        float4 wa1 = Wa4[(k4 * 4 + 1) * 32 + cg];
        float4 wa2 = Wa4[(k4 * 4 + 2) * 32 + cg];
        float4 wa3 = Wa4[(k4 * 4 + 3) * 32 + cg];
        float4 wb0 = Wb4[(k4 * 4 + 0) * 32 + cg];
        float4 wb1 = Wb4[(k4 * 4 + 1) * 32 + cg];
        float4 wb2 = Wb4[(k4 * 4 + 2) * 32 + cg];
        float4 wb3 = Wb4[(k4 * 4 + 3) * 32 + cg];
#pragma unroll
        for (int i = 0; i < 4; ++i) {
            float4 a = As4[(eg * 4 + i) * 32 + k4];
            accU[i][0] += a.x * wa0.x + a.y * wa1.x + a.z * wa2.x + a.w * wa3.x;
            accU[i][1] += a.x * wa0.y + a.y * wa1.y + a.z * wa2.y + a.w * wa3.y;
            accU[i][2] += a.x * wa0.z + a.y * wa1.z + a.z * wa2.z + a.w * wa3.z;
            accU[i][3] += a.x * wa0.w + a.y * wa1.w + a.z * wa2.w + a.w * wa3.w;
            accV[i][0] += a.x * wb0.x + a.y * wb1.x + a.z * wb2.x + a.w * wb3.x;
            accV[i][1] += a.x * wb0.y + a.y * wb1.y + a.z * wb2.y + a.w * wb3.y;
            accV[i][2] += a.x * wb0.z + a.y * wb1.z + a.z * wb2.z + a.w * wb3.z;
            accV[i][3] += a.x * wb0.w + a.y * wb1.w + a.z * wb2.w + a.w * wb3.w;
        }
    }
    __builtin_amdgcn_s_setprio(0);

#pragma unroll
    for (int i = 0; i < 4; ++i) {
        int r = row0 + eg * 4 + i;
        if (r < nrows) {
            reinterpret_cast<float4*>(U)[(size_t)r * 32 + cg] =
                make_float4(accU[i][0], accU[i][1], accU[i][2], accU[i][3]);
            reinterpret_cast<float4*>(V)[(size_t)r * 32 + cg] =
                make_float4(accV[i][0], accV[i][1], accV[i][2], accV[i][3]);
        }
    }
}

// ---------------- edge score (all 240K edges, one launch) ----------------

__global__ __launch_bounds__(256) void k_edge_score(const float* __restrict__ U,
                                                    const float* __restrict__ V,
                                                    const int* __restrict__ tp,
                                                    const int* __restrict__ tn,
                                                    const int* __restrict__ sp,
                                                    const int* __restrict__ sn,
                                                    const float* __restrict__ bl1,
                                                    const float* __restrict__ Wl2,
                                                    const float* __restrict__ bl2,
                                                    float* __restrict__ out) {
    const int t = threadIdx.x;
    const int f4 = t & 31;
    const int e = blockIdx.x * 8 + (t >> 5);
    if (e >= 2 * NTR + 2 * NTE) return;

    int a, bn;
    if (e < NTR)                { a = tp[e];              bn = tp[e + NTR]; }
    else if (e < 2 * NTR)       { a = tn[e - NTR];        bn = tn[e]; }
    else if (e < 2 * NTR + NTE) { a = sp[e - 2 * NTR];    bn = sp[e - 2 * NTR + NTE]; }
    else                        { a = sn[e - 2 * NTR - NTE]; bn = sn[e - 2 * NTR]; }

    float4 u = reinterpret_cast<const float4*>(U)[(size_t)a * 32 + f4];
    float4 v = reinterpret_cast<const float4*>(V)[(size_t)bn * 32 + f4];
    float4 bb = reinterpret_cast<const float4*>(bl1)[f4];
    float4 w2 = reinterpret_cast<const float4*>(Wl2)[f4];

    float s = fmaxf(u.x + v.x + bb.x, 0.f) * w2.x
            + fmaxf(u.y + v.y + bb.y, 0.f) * w2.y
            + fmaxf(u.z + v.z + bb.z, 0.f) * w2.z
            + fmaxf(u.w + v.w + bb.w, 0.f) * w2.w;
#pragma unroll
    for (int m = 16; m >= 1; m >>= 1) s += __shfl_xor(s, m, 64);
    if (f4 == 0) out[e] = s + bl2[0];
}

// ---------------- launch ----------------

extern "C" void kernel_launch(void* const* d_in, const int* in_sizes, int n_in,
                              void* d_out, int out_size, void* d_ws, size_t ws_size,
                              hipStream_t stream) {
    const float* x = (const float*)d_in[0];
    const int* ei = (const int*)d_in[1];
    const int* srcp = ei;
    const int* dstp = ei + NE;

    const int* e_tr_pos = (const int*)d_in[2];
    const int* e_tr_neg = (const int*)d_in[3];
    const int* e_te_pos = (const int*)d_in[4];
    const int* e_te_neg = (const int*)d_in[5];

    const float* W[4] = {(const float*)d_in[6], (const float*)d_in[8],
                         (const float*)d_in[10], (const float*)d_in[12]};
    const float* b[4] = {(const float*)d_in[7], (const float*)d_in[9],
                         (const float*)d_in[11], (const float*)d_in[13]};
    const float* Wl1 = (const float*)d_in[14];
    const float* bl1 = (const float*)d_in[15];
    const float* Wl2 = (const float*)d_in[16];
    const float* bl2 = (const float*)d_in[17];

    float* ws = (float*)d_ws;
    float* dis = ws;                          // [0, 50176)
    int* deg = (int*)(ws + 50176);
    int* offs = (int*)(ws + 100352);          // 50001 ints
    int* cursor = (int*)(ws + 150784);
    int* bsum = (int*)(ws + 200960);
    int* srcs = (int*)(ws + 201216);          // 800000 ints
    float* B0 = ws + 1001216;                 // hws0, hws2 / U
    float* B1 = B0 + 6400000;                 // hws1, hws3
    float* B2 = B1 + 6400000;                 // V ; head doubles as scan scratch
    int* partial = (int*)B2;                  // dead after scan3

    hipMemsetAsync(deg, 0, NN * sizeof(int), stream);
    k_count<<<(NE + 255) / 256, 256, 0, stream>>>(dstp, deg);
    k_scan1<<<SCAN_B, 256, 0, stream>>>(deg, partial, bsum, dis);
    k_scan3<<<SCAN_B, 256, 0, stream>>>(partial, bsum, offs, cursor);
    k_fill<<<(NE + 255) / 256, 256, 0, stream>>>(srcp, dstp, cursor, srcs);

    const int gemm_blocks = (NN + 31) / 32;   // 1563

    // hws0 = (x@W0)*dis
    k_gemm<<<gemm_blocks, 256, 0, stream>>>(x, W[0], dis, B0, NN);
    // fused middle layers
    k_fused_gg<<<gemm_blocks, 256, 0, stream>>>(B0, dis, b[0], W[1], offs, srcs, B1, NN);
    k_fused_gg<<<gemm_blocks, 256, 0, stream>>>(B1, dis, b[1], W[2], offs, srcs, B0, NN);
    k_fused_gg<<<gemm_blocks, 256, 0, stream>>>(B0, dis, b[2], W[3], offs, srcs, B1, NN);
    // fused tail: gather h4 (LDS only) -> U,V (merged dual-acc GEMM)
    float* Ubuf = B0;
    float* Vbuf = B2;
    k_fused_uv<<<gemm_blocks, 256, 0, stream>>>(B1, dis, b[3], Wl1, Wl1 + 128 * 128,
                                                offs, srcs, Ubuf, Vbuf, NN);

    float* out = (float*)d_out;
    const int n_all = 2 * NTR + 2 * NTE;
    k_edge_score<<<(n_all + 7) / 8, 256, 0, stream>>>(Ubuf, Vbuf,
                                                      e_tr_pos, e_tr_neg, e_te_pos, e_te_neg,
                                                      bl1, Wl2, bl2, out);
}

// Round 15
// 534.716 us; speedup vs baseline: 1.0278x; 1.0278x over previous
//
#include <hip/hip_runtime.h>
#include <math.h>

#define NN 50000
#define NE 800000
#define FD 128
#define SCAN_B 196   // ceil(50176/256)
#define NTR 100000
#define NTE 20000

// ---------------- degree ----------------

__global__ __launch_bounds__(256) void k_count(const int* __restrict__ dst, int* __restrict__ deg) {
    int e = blockIdx.x * 256 + threadIdx.x;
    if (e < NE) atomicAdd(&deg[dst[e]], 1);
}

// ---------------- parallel exclusive scan of deg ----------------

__global__ __launch_bounds__(256) void k_scan1(const int* __restrict__ deg,
                                               int* __restrict__ partial,
                                               int* __restrict__ bsum,
                                               float* __restrict__ dis) {
    __shared__ int wsum[4];
    const int t = threadIdx.x, lane = t & 63, wid = t >> 6;
    const int i = blockIdx.x * 256 + t;
    int v = (i < NN) ? deg[i] : 0;
    int sc = v;
#pragma unroll
    for (int d = 1; d < 64; d <<= 1) {
        int o = __shfl_up(sc, d, 64);
        if (lane >= d) sc += o;
    }
    if (lane == 63) wsum[wid] = sc;
    __syncthreads();
    int pre = 0;
    for (int w = 0; w < wid; ++w) pre += wsum[w];
    if (i < NN) {
        partial[i] = pre + sc - v;
        dis[i] = (float)(1.0 / sqrt((double)(v + 1)));
    }
    if (t == 255) bsum[blockIdx.x] = pre + sc;
}

// scan3 (scan2 folded in): each block reduces bsum[0..bid) itself, then adds.

__global__ __launch_bounds__(256) void k_scan3(const int* __restrict__ partial,
                                               const int* __restrict__ bsum,
                                               int* __restrict__ offs,
                                               int* __restrict__ cursor) {
    __shared__ int wsum[4];
    const int t = threadIdx.x, lane = t & 63, wid = t >> 6;
    int v = (t < blockIdx.x && t < SCAN_B) ? bsum[t] : 0;
#pragma unroll
    for (int m = 32; m >= 1; m >>= 1) v += __shfl_xor(v, m, 64);
    if (lane == 0) wsum[wid] = v;
    __syncthreads();
    int pre = wsum[0] + wsum[1] + wsum[2] + wsum[3];
    const int i = blockIdx.x * 256 + t;
    if (i < NN) {
        int o = partial[i] + pre;
        offs[i] = o;
        cursor[i] = o;
    }
    if (blockIdx.x == 0 && t == 0) offs[NN] = NE;
}

// ---------------- counting-sort fill ----------------

__global__ __launch_bounds__(256) void k_fill(const int* __restrict__ src, const int* __restrict__ dst,
                                              int* __restrict__ cursor, int* __restrict__ srcs_sorted) {
    int e = blockIdx.x * 256 + threadIdx.x;
    if (e < NE) {
        int d = dst[e];
        int p = atomicAdd(&cursor[d], 1);
        srcs_sorted[p] = src[e];
    }
}

// ---------------- node GEMM (layer 0): C[r] = (A[r] @ W) * dis[r] ----------------

__global__ __launch_bounds__(256) void k_gemm(const float* __restrict__ A,
                                              const float* __restrict__ W,
                                              const float* __restrict__ dis,
                                              float* __restrict__ C, int nrows) {
    __shared__ float As[32][128];
    const int t = threadIdx.x;
    const int row0 = blockIdx.x * 32;

    for (int idx = t; idx < 32 * 32; idx += 256) {
        int r = idx >> 5, c = idx & 31;
        float4 v = make_float4(0.f, 0.f, 0.f, 0.f);
        if (row0 + r < nrows)
            v = reinterpret_cast<const float4*>(A)[(size_t)(row0 + r) * 32 + c];
        reinterpret_cast<float4*>(&As[r][0])[c] = v;
    }
    __syncthreads();

    const int cg = t & 31;
    const int eg = t >> 5;
    float acc[4][4] = {{0.f}};

    const float4* W4 = reinterpret_cast<const float4*>(W);
    const float4* As4 = reinterpret_cast<const float4*>(As);

    float4 w0 = W4[0 * 32 + cg];
    float4 w1 = W4[1 * 32 + cg];
    float4 w2 = W4[2 * 32 + cg];
    float4 w3 = W4[3 * 32 + cg];

    for (int k4 = 0; k4 < 32; ++k4) {
        int kn = (k4 < 31) ? (k4 + 1) : 31;
        float4 n0 = W4[(kn * 4 + 0) * 32 + cg];
        float4 n1 = W4[(kn * 4 + 1) * 32 + cg];
        float4 n2 = W4[(kn * 4 + 2) * 32 + cg];
        float4 n3 = W4[(kn * 4 + 3) * 32 + cg];
#pragma unroll
        for (int i = 0; i < 4; ++i) {
            float4 a = As4[(eg * 4 + i) * 32 + k4];
            acc[i][0] += a.x * w0.x + a.y * w1.x + a.z * w2.x + a.w * w3.x;
            acc[i][1] += a.x * w0.y + a.y * w1.y + a.z * w2.y + a.w * w3.y;
            acc[i][2] += a.x * w0.z + a.y * w1.z + a.z * w2.z + a.w * w3.z;
            acc[i][3] += a.x * w0.w + a.y * w1.w + a.z * w2.w + a.w * w3.w;
        }
        w0 = n0; w1 = n1; w2 = n2; w3 = n3;
    }

#pragma unroll
    for (int i = 0; i < 4; ++i) {
        int r = row0 + eg * 4 + i;
        if (r < nrows) {
            float d = dis[r];
            float4 o = make_float4(acc[i][0] * d, acc[i][1] * d, acc[i][2] * d, acc[i][3] * d);
            reinterpret_cast<float4*>(C)[(size_t)r * 32 + cg] = o;
        }
    }
}

// ---------------- fused gather+GEMM, 32-row tile, barrier-free (R12 config, no setprio) ----

__global__ __launch_bounds__(256) void k_fused_gg(const float* __restrict__ hws_in,
                                                  const float* __restrict__ dis,
                                                  const float* __restrict__ bprev,
                                                  const float* __restrict__ W,
                                                  const int* __restrict__ offs,
                                                  const int* __restrict__ srcs,
                                                  float* __restrict__ hws_out, int nrows) {
    __shared__ float As[32][128];
    const int t = threadIdx.x;
    const int f4 = t & 31;
    const int ng = t >> 5;
    const int row0 = blockIdx.x * 32;

    const float4* H4 = reinterpret_cast<const float4*>(hws_in);
    float4 bb = reinterpret_cast<const float4*>(bprev)[f4];

#pragma unroll
    for (int j = 0; j < 4; ++j) {
        int nl = ng * 4 + j;
        int node = row0 + nl;
        float4 o = make_float4(0.f, 0.f, 0.f, 0.f);
        if (node < nrows) {
            float4 acc = H4[(size_t)node * 32 + f4];
            const int e0 = offs[node], e1 = offs[node + 1];
            int e = e0;
            for (; e + 8 <= e1; e += 8) {
                int s0 = srcs[e + 0], s1 = srcs[e + 1], s2 = srcs[e + 2], s3 = srcs[e + 3];
                int s4 = srcs[e + 4], s5 = srcs[e + 5], s6 = srcs[e + 6], s7 = srcs[e + 7];
                float4 v0 = H4[(size_t)s0 * 32 + f4];
                float4 v1 = H4[(size_t)s1 * 32 + f4];
                float4 v2 = H4[(size_t)s2 * 32 + f4];
                float4 v3 = H4[(size_t)s3 * 32 + f4];
                float4 v4 = H4[(size_t)s4 * 32 + f4];
                float4 v5 = H4[(size_t)s5 * 32 + f4];
                float4 v6 = H4[(size_t)s6 * 32 + f4];
                float4 v7 = H4[(size_t)s7 * 32 + f4];
                acc.x += ((v0.x + v1.x) + (v2.x + v3.x)) + ((v4.x + v5.x) + (v6.x + v7.x));
                acc.y += ((v0.y + v1.y) + (v2.y + v3.y)) + ((v4.y + v5.y) + (v6.y + v7.y));
                acc.z += ((v0.z + v1.z) + (v2.z + v3.z)) + ((v4.z + v5.z) + (v6.z + v7.z));
                acc.w += ((v0.w + v1.w) + (v2.w + v3.w)) + ((v4.w + v5.w) + (v6.w + v7.w));
            }
            for (; e < e1; ++e) {
                int s = srcs[e];
                float4 v = H4[(size_t)s * 32 + f4];
                acc.x += v.x; acc.y += v.y; acc.z += v.z; acc.w += v.w;
            }
            float d = dis[node];
            o.x = fmaxf(acc.x * d + bb.x, 0.f);
            o.y = fmaxf(acc.y * d + bb.y, 0.f);
            o.z = fmaxf(acc.z * d + bb.z, 0.f);
            o.w = fmaxf(acc.w * d + bb.w, 0.f);
        }
        reinterpret_cast<float4*>(&As[nl][0])[f4] = o;
    }
    asm volatile("s_waitcnt lgkmcnt(0)" ::: "memory");

    const int cg = f4;
    const int eg = ng;
    float acc[4][4] = {{0.f}};

    const float4* W4 = reinterpret_cast<const float4*>(W);
    const float4* As4 = reinterpret_cast<const float4*>(As);

    float4 w0 = W4[0 * 32 + cg];
    float4 w1 = W4[1 * 32 + cg];
    float4 w2 = W4[2 * 32 + cg];
    float4 w3 = W4[3 * 32 + cg];

    for (int k4 = 0; k4 < 32; ++k4) {
        int kn = (k4 < 31) ? (k4 + 1) : 31;
        float4 n0 = W4[(kn * 4 + 0) * 32 + cg];
        float4 n1 = W4[(kn * 4 + 1) * 32 + cg];
        float4 n2 = W4[(kn * 4 + 2) * 32 + cg];
        float4 n3 = W4[(kn * 4 + 3) * 32 + cg];
#pragma unroll
        for (int i = 0; i < 4; ++i) {
            float4 a = As4[(eg * 4 + i) * 32 + k4];
            acc[i][0] += a.x * w0.x + a.y * w1.x + a.z * w2.x + a.w * w3.x;
            acc[i][1] += a.x * w0.y + a.y * w1.y + a.z * w2.y + a.w * w3.y;
            acc[i][2] += a.x * w0.z + a.y * w1.z + a.z * w2.z + a.w * w3.z;
            acc[i][3] += a.x * w0.w + a.y * w1.w + a.z * w2.w + a.w * w3.w;
        }
        w0 = n0; w1 = n1; w2 = n2; w3 = n3;
    }

#pragma unroll
    for (int i = 0; i < 4; ++i) {
        int r = row0 + eg * 4 + i;
        if (r < nrows) {
            float d = dis[r];
            float4 o = make_float4(acc[i][0] * d, acc[i][1] * d, acc[i][2] * d, acc[i][3] * d);
            reinterpret_cast<float4*>(hws_out)[(size_t)r * 32 + cg] = o;
        }
    }
}

// ---------------- fused tail: gather h4 (LDS only) -> U,V in ONE merged k-loop (no setprio) ----

__global__ __launch_bounds__(256) void k_fused_uv(const float* __restrict__ hws_in,
                                                  const float* __restrict__ dis,
                                                  const float* __restrict__ bprev,
                                                  const float* __restrict__ Wa,
                                                  const float* __restrict__ Wb,
                                                  const int* __restrict__ offs,
                                                  const int* __restrict__ srcs,
                                                  float* __restrict__ U,
                                                  float* __restrict__ V, int nrows) {
    __shared__ float As[32][128];
    const int t = threadIdx.x;
    const int f4 = t & 31;
    const int ng = t >> 5;
    const int row0 = blockIdx.x * 32;

    const float4* H4 = reinterpret_cast<const float4*>(hws_in);
    float4 bb = reinterpret_cast<const float4*>(bprev)[f4];

#pragma unroll
    for (int j = 0; j < 4; ++j) {
        int nl = ng * 4 + j;
        int node = row0 + nl;
        float4 o = make_float4(0.f, 0.f, 0.f, 0.f);
        if (node < nrows) {
            float4 acc = H4[(size_t)node * 32 + f4];
            const int e0 = offs[node], e1 = offs[node + 1];
            int e = e0;
            for (; e + 8 <= e1; e += 8) {
                int s0 = srcs[e + 0], s1 = srcs[e + 1], s2 = srcs[e + 2], s3 = srcs[e + 3];
                int s4 = srcs[e + 4], s5 = srcs[e + 5], s6 = srcs[e + 6], s7 = srcs[e + 7];
                float4 v0 = H4[(size_t)s0 * 32 + f4];
                float4 v1 = H4[(size_t)s1 * 32 + f4];
                float4 v2 = H4[(size_t)s2 * 32 + f4];
                float4 v3 = H4[(size_t)s3 * 32 + f4];
                float4 v4 = H4[(size_t)s4 * 32 + f4];
                float4 v5 = H4[(size_t)s5 * 32 + f4];
                float4 v6 = H4[(size_t)s6 * 32 + f4];
                float4 v7 = H4[(size_t)s7 * 32 + f4];
                acc.x += ((v0.x + v1.x) + (v2.x + v3.x)) + ((v4.x + v5.x) + (v6.x + v7.x));
                acc.y += ((v0.y + v1.y) + (v2.y + v3.y)) + ((v4.y + v5.y) + (v6.y + v7.y));
                acc.z += ((v0.z + v1.z) + (v2.z + v3.z)) + ((v4.z + v5.z) + (v6.z + v7.z));
                acc.w += ((v0.w + v1.w) + (v2.w + v3.w)) + ((v4.w + v5.w) + (v6.w + v7.w));
            }
            for (; e < e1; ++e) {
                int s = srcs[e];
                float4 v = H4[(size_t)s * 32 + f4];
                acc.x += v.x; acc.y += v.y; acc.z += v.z; acc.w += v.w;
            }
            float d = dis[node];
            o.x = acc.x * d + bb.x;
            o.y = acc.y * d + bb.y;
            o.z = acc.z * d + bb.z;
            o.w = acc.w * d + bb.w;
        }
        reinterpret_cast<float4*>(&As[nl][0])[f4] = o;
    }
    asm volatile("s_waitcnt lgkmcnt(0)" ::: "memory");

    const int cg = f4;
    const int eg = ng;
    const float4* As4 = reinterpret_cast<const float4*>(As);
    const float4* Wa4 = reinterpret_cast<const float4*>(Wa);
    const float4* Wb4 = reinterpret_cast<const float4*>(Wb);

    float accU[4][4] = {{0.f}};
    float accV[4][4] = {{0.f}};

    for (int k4 = 0; k4 < 32; ++k4) {
        float4 wa0 = Wa4[(k4 * 4 + 0) * 32 + cg];
        float4 wa1 = Wa4[(k4 * 4 + 1) * 32 + cg];
        float4 wa2 = Wa4[(k4 * 4 + 2) * 32 + cg];
        float4 wa3 = Wa4[(k4 * 4 + 3) * 32 + cg];
        float4 wb0 = Wb4[(k4 * 4 + 0) * 32 + cg];
        float4 wb1 = Wb4[(k4 * 4 + 1) * 32 + cg];
        float4 wb2 = Wb4[(k4 * 4 + 2) * 32 + cg];
        float4 wb3 = Wb4[(k4 * 4 + 3) * 32 + cg];
#pragma unroll
        for (int i = 0; i < 4; ++i) {
            float4 a = As4[(eg * 4 + i) * 32 + k4];
            accU[i][0] += a.x * wa0.x + a.y * wa1.x + a.z * wa2.x + a.w * wa3.x;
            accU[i][1] += a.x * wa0.y + a.y * wa1.y + a.z * wa2.y + a.w * wa3.y;
            accU[i][2] += a.x * wa0.z + a.y * wa1.z + a.z * wa2.z + a.w * wa3.z;
            accU[i][3] += a.x * wa0.w + a.y * wa1.w + a.z * wa2.w + a.w * wa3.w;
            accV[i][0] += a.x * wb0.x + a.y * wb1.x + a.z * wb2.x + a.w * wb3.x;
            accV[i][1] += a.x * wb0.y + a.y * wb1.y + a.z * wb2.y + a.w * wb3.y;
            accV[i][2] += a.x * wb0.z + a.y * wb1.z + a.z * wb2.z + a.w * wb3.z;
            accV[i][3] += a.x * wb0.w + a.y * wb1.w + a.z * wb2.w + a.w * wb3.w;
        }
    }

#pragma unroll
    for (int i = 0; i < 4; ++i) {
        int r = row0 + eg * 4 + i;
        if (r < nrows) {
            reinterpret_cast<float4*>(U)[(size_t)r * 32 + cg] =
                make_float4(accU[i][0], accU[i][1], accU[i][2], accU[i][3]);
            reinterpret_cast<float4*>(V)[(size_t)r * 32 + cg] =
                make_float4(accV[i][0], accV[i][1], accV[i][2], accV[i][3]);
        }
    }
}

// ---------------- edge score (all 240K edges, one launch) ----------------

__global__ __launch_bounds__(256) void k_edge_score(const float* __restrict__ U,
                                                    const float* __restrict__ V,
                                                    const int* __restrict__ tp,
                                                    const int* __restrict__ tn,
                                                    const int* __restrict__ sp,
                                                    const int* __restrict__ sn,
                                                    const float* __restrict__ bl1,
                                                    const float* __restrict__ Wl2,
                                                    const float* __restrict__ bl2,
                                                    float* __restrict__ out) {
    const int t = threadIdx.x;
    const int f4 = t & 31;
    const int e = blockIdx.x * 8 + (t >> 5);
    if (e >= 2 * NTR + 2 * NTE) return;

    int a, bn;
    if (e < NTR)                { a = tp[e];              bn = tp[e + NTR]; }
    else if (e < 2 * NTR)       { a = tn[e - NTR];        bn = tn[e]; }
    else if (e < 2 * NTR + NTE) { a = sp[e - 2 * NTR];    bn = sp[e - 2 * NTR + NTE]; }
    else                        { a = sn[e - 2 * NTR - NTE]; bn = sn[e - 2 * NTR]; }

    float4 u = reinterpret_cast<const float4*>(U)[(size_t)a * 32 + f4];
    float4 v = reinterpret_cast<const float4*>(V)[(size_t)bn * 32 + f4];
    float4 bb = reinterpret_cast<const float4*>(bl1)[f4];
    float4 w2 = reinterpret_cast<const float4*>(Wl2)[f4];

    float s = fmaxf(u.x + v.x + bb.x, 0.f) * w2.x
            + fmaxf(u.y + v.y + bb.y, 0.f) * w2.y
            + fmaxf(u.z + v.z + bb.z, 0.f) * w2.z
            + fmaxf(u.w + v.w + bb.w, 0.f) * w2.w;
#pragma unroll
    for (int m = 16; m >= 1; m >>= 1) s += __shfl_xor(s, m, 64);
    if (f4 == 0) out[e] = s + bl2[0];
}

// ---------------- launch ----------------

extern "C" void kernel_launch(void* const* d_in, const int* in_sizes, int n_in,
                              void* d_out, int out_size, void* d_ws, size_t ws_size,
                              hipStream_t stream) {
    const float* x = (const float*)d_in[0];
    const int* ei = (const int*)d_in[1];
    const int* srcp = ei;
    const int* dstp = ei + NE;

    const int* e_tr_pos = (const int*)d_in[2];
    const int* e_tr_neg = (const int*)d_in[3];
    const int* e_te_pos = (const int*)d_in[4];
    const int* e_te_neg = (const int*)d_in[5];

    const float* W[4] = {(const float*)d_in[6], (const float*)d_in[8],
                         (const float*)d_in[10], (const float*)d_in[12]};
    const float* b[4] = {(const float*)d_in[7], (const float*)d_in[9],
                         (const float*)d_in[11], (const float*)d_in[13]};
    const float* Wl1 = (const float*)d_in[14];
    const float* bl1 = (const float*)d_in[15];
    const float* Wl2 = (const float*)d_in[16];
    const float* bl2 = (const float*)d_in[17];

    float* ws = (float*)d_ws;
    float* dis = ws;                          // [0, 50176)
    int* deg = (int*)(ws + 50176);
    int* offs = (int*)(ws + 100352);          // 50001 ints
    int* cursor = (int*)(ws + 150784);
    int* bsum = (int*)(ws + 200960);
    int* srcs = (int*)(ws + 201216);          // 800000 ints
    float* B0 = ws + 1001216;                 // hws0, hws2 / U
    float* B1 = B0 + 6400000;                 // hws1, hws3
    float* B2 = B1 + 6400000;                 // V ; head doubles as scan scratch
    int* partial = (int*)B2;                  // dead after scan3

    hipMemsetAsync(deg, 0, NN * sizeof(int), stream);
    k_count<<<(NE + 255) / 256, 256, 0, stream>>>(dstp, deg);
    k_scan1<<<SCAN_B, 256, 0, stream>>>(deg, partial, bsum, dis);
    k_scan3<<<SCAN_B, 256, 0, stream>>>(partial, bsum, offs, cursor);
    k_fill<<<(NE + 255) / 256, 256, 0, stream>>>(srcp, dstp, cursor, srcs);

    const int gemm_blocks = (NN + 31) / 32;   // 1563

    // hws0 = (x@W0)*dis
    k_gemm<<<gemm_blocks, 256, 0, stream>>>(x, W[0], dis, B0, NN);
    // fused middle layers
    k_fused_gg<<<gemm_blocks, 256, 0, stream>>>(B0, dis, b[0], W[1], offs, srcs, B1, NN);
    k_fused_gg<<<gemm_blocks, 256, 0, stream>>>(B1, dis, b[1], W[2], offs, srcs, B0, NN);
    k_fused_gg<<<gemm_blocks, 256, 0, stream>>>(B0, dis, b[2], W[3], offs, srcs, B1, NN);
    // fused tail: gather h4 (LDS only) -> U,V (merged dual-acc GEMM)
    float* Ubuf = B0;
    float* Vbuf = B2;
    k_fused_uv<<<gemm_blocks, 256, 0, stream>>>(B1, dis, b[3], Wl1, Wl1 + 128 * 128,
                                                offs, srcs, Ubuf, Vbuf, NN);

    float* out = (float*)d_out;
    const int n_all = 2 * NTR + 2 * NTE;
    k_edge_score<<<(n_all + 7) / 8, 256, 0, stream>>>(Ubuf, Vbuf,
                                                      e_tr_pos, e_tr_neg, e_te_pos, e_te_neg,
                                                      bl1, Wl2, bl2, out);
}